// Round 2
// baseline (3743.592 us; speedup 1.0000x reference)
//
#include <hip/hip_runtime.h>
#include <cstddef>

// ---------------- problem constants ----------------
constexpr int B = 8, NC1 = 64, NC2 = 32, ZD = 512;
constexpr int HI = 128, WI = 128, HO = 256, WO = 256;
constexpr float EPS_DEMOD_F = 1e-8f;
constexpr float EPS_BN_F = 1e-5f;
constexpr float UP_STEP = 127.0f / 255.0f;   // linspace step, float32 exact-compile-time

// ---------------- workspace layout (float offsets), total ~203 MB ----------------
constexpr size_t OFF_Y1   = 0;                                   // B*NC1
constexpr size_t OFF_Y2   = OFF_Y1 + (size_t)B * NC1;            // B*NC1
constexpr size_t OFF_W1   = OFF_Y2 + (size_t)B * NC1;            // B*NC1*NC1*9
constexpr size_t OFF_W2   = OFF_W1 + (size_t)B * NC1 * NC1 * 9;  // B*NC2*NC1*9
constexpr size_t OFF_OUT1 = OFF_W2 + (size_t)B * NC2 * NC1 * 9;  // B*NC1*HO*WO (128MB)
constexpr size_t OFF_SC   = OFF_OUT1 + (size_t)B * NC1 * HO * WO;// B*NC2*HO*WO (64MB)
constexpr size_t OFF_STATS= OFF_SC + (size_t)B * NC2 * HO * WO;  // 2*NC2

// ---------------- helpers ----------------
__device__ __forceinline__ float mish_f(float x) {
    // mish(x) = x * tanh(softplus(x)) = x * ((1+e^x)^2 - 1)/((1+e^x)^2 + 1)  (exact identity)
    if (x > 20.0f) return x;          // tanh saturated to 1 within fp32 ulp
    float e = expf(x);
    float a = 1.0f + e;
    float a2 = a * a;
    return x * (a2 - 1.0f) / (a2 + 1.0f);
}

// ---------------- kernel 1: y = z @ sw.T + sb for both style layers ----------------
__global__ void style_y_kernel(const float* __restrict__ z,
                               const float* __restrict__ w1, const float* __restrict__ b1,
                               const float* __restrict__ w2, const float* __restrict__ b2,
                               float* __restrict__ y1, float* __restrict__ y2) {
    int gid = blockIdx.x * blockDim.x + threadIdx.x;   // 0..1023
    if (gid >= 2 * B * NC1) return;
    int which = gid >> 9;        // 0: conv1, 1: conv2
    int r = gid & 511;
    int b = r >> 6, c = r & 63;
    const float* w = which ? w2 : w1;
    const float* bias = which ? b2 : b1;
    const float* zr = z + (size_t)b * ZD;
    const float* wr = w + (size_t)c * ZD;
    float acc = 0.f;
    for (int k = 0; k < ZD; k += 4) {
        float4 zv = *reinterpret_cast<const float4*>(zr + k);
        float4 wv = *reinterpret_cast<const float4*>(wr + k);
        acc += zv.x * wv.x + zv.y * wv.y + zv.z * wv.z + zv.w * wv.w;
    }
    acc += bias[c];
    (which ? y2 : y1)[r] = acc;
}

// ---------------- kernel 2: modulate + demodulate weights ----------------
// one 64-thread block per (conv, b, oc); thread t handles input channel t
__global__ void modulate_kernel(const float* __restrict__ conv1_w, const float* __restrict__ conv2_w,
                                const float* __restrict__ y1, const float* __restrict__ y2,
                                float* __restrict__ w1m, float* __restrict__ w2m) {
    int bid = blockIdx.x;
    int ic = threadIdx.x;     // 0..63
    const float* src; float* dst; const float* y; int oc, b, OC;
    if (bid < B * NC1) {
        b = bid >> 6; oc = bid & 63; OC = NC1; src = conv1_w; dst = w1m; y = y1;
    } else {
        int r = bid - B * NC1; b = r >> 5; oc = r & 31; OC = NC2; src = conv2_w; dst = w2m; y = y2;
    }
    float m = 1.0f + y[b * NC1 + ic];
    const float* s = src + (size_t)(oc * NC1 + ic) * 9;
    float wv[9];
    float ss = 0.f;
    #pragma unroll
    for (int k = 0; k < 9; ++k) { wv[k] = s[k] * m; ss += wv[k] * wv[k]; }
    #pragma unroll
    for (int off = 1; off < 64; off <<= 1) ss += __shfl_xor(ss, off);
    float d = rsqrtf(ss + EPS_DEMOD_F);
    float* o = dst + (((size_t)b * OC + oc) * NC1 + ic) * 9;
    #pragma unroll
    for (int k = 0; k < 9; ++k) o[k] = wv[k] * d;
}

// ---------------- kernel 3: direct 3x3 conv, pad 1, optional fused x2-bilinear input ----------------
// IC = 64 fixed. Tile: 64(W) x 32(H) output pixels, 8 output channels per block, 256 threads.
// tx = tid&15 -> 4 cols each, ty = tid>>4 -> 2 rows each.
// Weights via block-uniform addresses (s_load path), input staged in LDS 4 ch at a time.
// UPS: `in` is (B,64,128,128); staging applies align_corners bilinear x2 on the fly
//      using per-block coordinate tables (H-lerp first, then W — matches reference rounding).
// LDS pitch 68: b128 fragment reads are ~2-way bank-conflicted, but LDS-pipe cycles
// (~384/CU/chunk) are 3x under the FMA issue cycles (~1152/SIMD/chunk) -> hidden; keep.
template<bool UPS, bool PER_BATCH, bool MISH, bool STATS>
__global__ __launch_bounds__(256) void conv3x3_kernel(
        const float* __restrict__ in, const float* __restrict__ wgt,
        float* __restrict__ out, float* __restrict__ stats,
        int OC, int ocShift) {
    __shared__ float smem[4][34][68];
    __shared__ int   yot[34], ydt[34], xot[66], xdt[66];
    __shared__ float wyt[34], wxt[66];

    const int tid = threadIdx.x;
    const int tx = tid & 15, ty = tid >> 4;
    const int bid = blockIdx.x;
    const int tileX = bid & 3;
    const int tileY = (bid >> 2) & 7;
    const int rest = bid >> 5;
    const int ocT = rest & ((1 << ocShift) - 1);
    const int b = rest >> ocShift;
    const int row0 = tileY * 32, col0 = tileX * 64;

    if constexpr (UPS) {
        // coordinate tables for the 34x66 upsampled halo window
        if (tid < 34) {
            int gy = row0 - 1 + tid;
            if ((unsigned)gy < 256u) {
                float fy = (float)gy * UP_STEP;
                int y0 = (int)fy;
                yot[tid] = y0 << 7;                  // y0 * 128
                ydt[tid] = (y0 < HI - 1) ? WI : 0;   // row stride to y1
                wyt[tid] = fy - (float)y0;
            }
        } else if (tid >= 64 && tid < 130) {
            int xx = tid - 64;
            int gx = col0 - 1 + xx;
            if ((unsigned)gx < 256u) {
                float fx = (float)gx * UP_STEP;
                int x0 = (int)fx;
                xot[xx] = x0;
                xdt[xx] = (x0 < WI - 1) ? 1 : 0;
                wxt[xx] = fx - (float)x0;
            }
        }
        __syncthreads();
    }

    const float* wbase = wgt + ((PER_BATCH ? (size_t)b * OC : (size_t)0) + (size_t)(ocT << 3)) * (NC1 * 9);

    float acc[8][2][4];
    #pragma unroll
    for (int o = 0; o < 8; ++o)
        #pragma unroll
        for (int dy = 0; dy < 2; ++dy)
            #pragma unroll
            for (int dx = 0; dx < 4; ++dx) acc[o][dy][dx] = 0.f;

    for (int ch = 0; ch < NC1; ch += 4) {
        #pragma unroll
        for (int c = 0; c < 4; ++c) {
            if constexpr (UPS) {
                const float* ibase = in + ((size_t)(b * NC1 + ch + c) << 14);   // 128*128
                for (int i = tid; i < 34 * 66; i += 256) {
                    int yy = i / 66;
                    int xx = i - yy * 66;
                    int gy = row0 - 1 + yy, gx = col0 - 1 + xx;
                    float v = 0.f;
                    if ((unsigned)gy < 256u && (unsigned)gx < 256u) {
                        int yo = yot[yy], yd = ydt[yy]; float wy = wyt[yy];
                        int xo = xot[xx], xd = xdt[xx]; float wx = wxt[xx];
                        const float* bp = ibase + yo + xo;
                        float v00 = bp[0], v01 = bp[xd];
                        float v10 = bp[yd], v11 = bp[yd + xd];
                        float r0 = v00 * (1.0f - wy) + v10 * wy;   // H first (matches ref)
                        float r1 = v01 * (1.0f - wy) + v11 * wy;
                        v = r0 * (1.0f - wx) + r1 * wx;            // then W
                    }
                    smem[c][yy][xx] = v;
                }
            } else {
                const float* ibase = in + ((size_t)(b * NC1 + ch + c) << 16);   // 256*256
                for (int i = tid; i < 34 * 66; i += 256) {
                    int yy = i / 66;
                    int xx = i - yy * 66;
                    int gy = row0 - 1 + yy, gx = col0 - 1 + xx;
                    float v = 0.f;
                    if ((unsigned)gy < 256u && (unsigned)gx < 256u)
                        v = ibase[(gy << 8) + gx];
                    smem[c][yy][xx] = v;
                }
            }
        }
        __syncthreads();
        #pragma unroll
        for (int c = 0; c < 4; ++c) {
            float xi[4][6];
            #pragma unroll
            for (int r = 0; r < 4; ++r) {
                const float* rowp = &smem[c][2 * ty + r][4 * tx];
                float4 v4 = *reinterpret_cast<const float4*>(rowp);
                float2 v2 = *reinterpret_cast<const float2*>(rowp + 4);
                xi[r][0] = v4.x; xi[r][1] = v4.y; xi[r][2] = v4.z; xi[r][3] = v4.w;
                xi[r][4] = v2.x; xi[r][5] = v2.y;
            }
            #pragma unroll
            for (int o = 0; o < 8; ++o) {
                const float* wr = wbase + (size_t)(o * NC1 + ch + c) * 9;  // block-uniform -> s_load
                float w[9];
                #pragma unroll
                for (int k = 0; k < 9; ++k) w[k] = wr[k];
                #pragma unroll
                for (int kh = 0; kh < 3; ++kh)
                    #pragma unroll
                    for (int kw = 0; kw < 3; ++kw) {
                        float wv = w[kh * 3 + kw];
                        #pragma unroll
                        for (int dy = 0; dy < 2; ++dy)
                            #pragma unroll
                            for (int dx = 0; dx < 4; ++dx)
                                acc[o][dy][dx] = fmaf(xi[dy + kh][dx + kw], wv, acc[o][dy][dx]);
                    }
            }
        }
        __syncthreads();
    }

    // epilogue: store (optionally mish), optionally accumulate BN stats
    #pragma unroll
    for (int o = 0; o < 8; ++o) {
        int ocg = (ocT << 3) + o;
        float* obase = out + (((size_t)(b * OC + ocg)) << 16) + ((size_t)(row0 + 2 * ty) << 8) + col0 + 4 * tx;
        #pragma unroll
        for (int dy = 0; dy < 2; ++dy) {
            float4 v;
            v.x = MISH ? mish_f(acc[o][dy][0]) : acc[o][dy][0];
            v.y = MISH ? mish_f(acc[o][dy][1]) : acc[o][dy][1];
            v.z = MISH ? mish_f(acc[o][dy][2]) : acc[o][dy][2];
            v.w = MISH ? mish_f(acc[o][dy][3]) : acc[o][dy][3];
            *reinterpret_cast<float4*>(obase + ((size_t)dy << 8)) = v;
        }
    }

    if constexpr (STATS) {
        #pragma unroll
        for (int o = 0; o < 8; ++o) {
            float s = 0.f, s2 = 0.f;
            #pragma unroll
            for (int dy = 0; dy < 2; ++dy)
                #pragma unroll
                for (int dx = 0; dx < 4; ++dx) { float v = acc[o][dy][dx]; s += v; s2 += v * v; }
            #pragma unroll
            for (int off = 1; off < 64; off <<= 1) {
                s += __shfl_xor(s, off);
                s2 += __shfl_xor(s2, off);
            }
            if ((tid & 63) == 0) {
                atomicAdd(&stats[2 * ((ocT << 3) + o) + 0], s);
                atomicAdd(&stats[2 * ((ocT << 3) + o) + 1], s2);
            }
        }
    }
}

// ---------------- kernel 4: BN finalize + residual add (in-place on d_out) ----------------
__global__ void final_kernel(float* __restrict__ out, const float* __restrict__ sc,
                             const float* __restrict__ stats, const float* __restrict__ gamma,
                             const float* __restrict__ beta) {
    const int n4 = B * NC2 * HO * WO / 4;
    const float inv_cnt = 1.0f / (float)(B * HO * WO);
    for (int i = blockIdx.x * blockDim.x + threadIdx.x; i < n4; i += gridDim.x * blockDim.x) {
        int c = (i >> 14) & 31;    // channel stride 65536 elems = 16384 float4s
        float mean = stats[2 * c] * inv_cnt;
        float var = stats[2 * c + 1] * inv_cnt - mean * mean;
        float g = gamma[c] * rsqrtf(var + EPS_BN_F);
        float bt = beta[c] - mean * g;     // sc conv bias cancels exactly in batch-stats BN
        float4 a = reinterpret_cast<float4*>(out)[i];
        float4 s = reinterpret_cast<const float4*>(sc)[i];
        float4 o;
        o.x = a.x + s.x * g + bt;
        o.y = a.y + s.y * g + bt;
        o.z = a.z + s.z * g + bt;
        o.w = a.w + s.w * g + bt;
        reinterpret_cast<float4*>(out)[i] = o;
    }
}

// ---------------- launch ----------------
extern "C" void kernel_launch(void* const* d_in, const int* in_sizes, int n_in,
                              void* d_out, int out_size, void* d_ws, size_t ws_size,
                              hipStream_t stream) {
    (void)in_sizes; (void)n_in; (void)out_size; (void)ws_size;
    const float* input   = (const float*)d_in[0];
    const float* z       = (const float*)d_in[1];
    const float* ws1_w   = (const float*)d_in[2];
    const float* ws1_b   = (const float*)d_in[3];
    const float* conv1_w = (const float*)d_in[4];
    const float* ws2_w   = (const float*)d_in[5];
    const float* ws2_b   = (const float*)d_in[6];
    const float* conv2_w = (const float*)d_in[7];
    const float* sc_w    = (const float*)d_in[8];
    // d_in[9] = sc_b: cancels exactly under training-mode BN (shifts mean only)
    const float* bn_gamma = (const float*)d_in[10];
    const float* bn_beta  = (const float*)d_in[11];

    float* ws   = (float*)d_ws;
    float* y1   = ws + OFF_Y1;
    float* y2   = ws + OFF_Y2;
    float* w1m  = ws + OFF_W1;
    float* w2m  = ws + OFF_W2;
    float* out1 = ws + OFF_OUT1;
    float* sc   = ws + OFF_SC;
    float* stats= ws + OFF_STATS;
    float* outp = (float*)d_out;

    hipMemsetAsync(stats, 0, 2 * NC2 * sizeof(float), stream);

    style_y_kernel<<<4, 256, 0, stream>>>(z, ws1_w, ws1_b, ws2_w, ws2_b, y1, y2);
    modulate_kernel<<<B * NC1 + B * NC2, 64, 0, stream>>>(conv1_w, conv2_w, y1, y2, w1m, w2m);

    // conv1: input --(fused x2 bilinear)--> conv -> out1 (B,64,256,256), per-batch weights, mish
    conv3x3_kernel<true, true, true, false><<<2048, 256, 0, stream>>>(input, w1m, out1, nullptr, NC1, 3);
    // shortcut: input --(fused x2 bilinear)--> conv -> sc (B,32,256,256), shared weights, BN stats
    conv3x3_kernel<true, false, false, true><<<1024, 256, 0, stream>>>(input, sc_w, sc, stats, NC2, 2);
    // conv2: out1 -> d_out (B,32,256,256), per-batch weights, mish
    conv3x3_kernel<false, true, true, false><<<1024, 256, 0, stream>>>(out1, w2m, outp, nullptr, NC2, 2);

    // out = out2 + gamma_hat * sc + beta_hat   (in place on d_out)
    final_kernel<<<2048, 256, 0, stream>>>(outp, sc, stats, bn_gamma, bn_beta);
}

// Round 3
// 2977.636 us; speedup vs baseline: 1.2572x; 1.2572x over previous
//
#include <hip/hip_runtime.h>
#include <cstddef>

// ---------------- problem constants ----------------
constexpr int B = 8, NC1 = 64, NC2 = 32, ZD = 512;
constexpr int HI = 128, WI = 128, HO = 256, WO = 256;
constexpr float EPS_DEMOD_F = 1e-8f;
constexpr float EPS_BN_F = 1e-5f;
constexpr float UP_STEP = 127.0f / 255.0f;

// ---------------- workspace layout (float offsets) ----------------
constexpr size_t OFF_Y1   = 0;                                    // 512
constexpr size_t OFF_Y2   = OFF_Y1 + (size_t)B * NC1;             // 512
constexpr size_t OFF_W1   = OFF_Y2 + (size_t)B * NC1;             // 294912
constexpr size_t OFF_W2   = OFF_W1 + (size_t)B * NC1 * NC1 * 9;   // 147456
constexpr size_t OFF_STATS= OFF_W2 + (size_t)B * NC2 * NC1 * 9;   // 64
constexpr size_t OFF_SC   = OFF_STATS + 64;                       // 16.78M floats
constexpr size_t OFF_OUT1 = OFF_SC + (size_t)B * NC2 * HO * WO;   // 33.55M floats
constexpr size_t OFF_UP   = OFF_OUT1 + (size_t)B * NC1 * HO * WO; // 33.55M floats (materialized path only)
constexpr size_t END_FUSED = OFF_UP;                              // fused path high-water
constexpr size_t END_MAT   = OFF_UP + (size_t)B * NC1 * HO * WO;
constexpr size_t NEED_MAT_BYTES = END_MAT * 4;                    // ~337 MB

// ---------------- helpers ----------------
__device__ __forceinline__ float mish_f(float x) {
    // mish(x) = x * ((1+e^x)^2 - 1)/((1+e^x)^2 + 1)  (exact identity)
    if (x > 20.0f) return x;          // tanh saturated within fp32 ulp
    float e = expf(x);
    float a = 1.0f + e;
    float a2 = a * a;
    return x * (a2 - 1.0f) / (a2 + 1.0f);
}

// ---------------- kernel 1: y = z @ sw.T + sb for both style layers ----------------
__global__ void style_y_kernel(const float* __restrict__ z,
                               const float* __restrict__ w1, const float* __restrict__ b1,
                               const float* __restrict__ w2, const float* __restrict__ b2,
                               float* __restrict__ y1, float* __restrict__ y2) {
    int gid = blockIdx.x * blockDim.x + threadIdx.x;   // 0..1023
    if (gid >= 2 * B * NC1) return;
    int which = gid >> 9;
    int r = gid & 511;
    int b = r >> 6, c = r & 63;
    const float* w = which ? w2 : w1;
    const float* bias = which ? b2 : b1;
    const float* zr = z + (size_t)b * ZD;
    const float* wr = w + (size_t)c * ZD;
    float acc = 0.f;
    for (int k = 0; k < ZD; k += 4) {
        float4 zv = *reinterpret_cast<const float4*>(zr + k);
        float4 wv = *reinterpret_cast<const float4*>(wr + k);
        acc += zv.x * wv.x + zv.y * wv.y + zv.z * wv.z + zv.w * wv.w;
    }
    acc += bias[c];
    (which ? y2 : y1)[r] = acc;
}

// ---------------- kernel 2: modulate + demodulate weights ----------------
__global__ void modulate_kernel(const float* __restrict__ conv1_w, const float* __restrict__ conv2_w,
                                const float* __restrict__ y1, const float* __restrict__ y2,
                                float* __restrict__ w1m, float* __restrict__ w2m) {
    int bid = blockIdx.x;
    int ic = threadIdx.x;     // 0..63
    const float* src; float* dst; const float* y; int oc, b, OC;
    if (bid < B * NC1) {
        b = bid >> 6; oc = bid & 63; OC = NC1; src = conv1_w; dst = w1m; y = y1;
    } else {
        int r = bid - B * NC1; b = r >> 5; oc = r & 31; OC = NC2; src = conv2_w; dst = w2m; y = y2;
    }
    float m = 1.0f + y[b * NC1 + ic];
    const float* s = src + (size_t)(oc * NC1 + ic) * 9;
    float wv[9];
    float ss = 0.f;
    #pragma unroll
    for (int k = 0; k < 9; ++k) { wv[k] = s[k] * m; ss += wv[k] * wv[k]; }
    #pragma unroll
    for (int off = 1; off < 64; off <<= 1) ss += __shfl_xor(ss, off);
    float d = rsqrtf(ss + EPS_DEMOD_F);
    float* o = dst + (((size_t)b * OC + oc) * NC1 + ic) * 9;
    #pragma unroll
    for (int k = 0; k < 9; ++k) o[k] = wv[k] * d;
}

// ---------------- kernel 3: bilinear x2 upsample (materialized path) ----------------
__global__ void upsample_kernel(const float* __restrict__ in, float* __restrict__ out) {
    const int n = B * NC1 * HO * WO;
    for (int idx = blockIdx.x * blockDim.x + threadIdx.x; idx < n; idx += gridDim.x * blockDim.x) {
        int ox = idx & 255;
        int oy = (idx >> 8) & 255;
        int bc = idx >> 16;
        float fy = oy * UP_STEP; int y0 = (int)fy; float wy = fy - (float)y0; int y1i = y0 + (y0 < HI - 1);
        float fx = ox * UP_STEP; int x0 = (int)fx; float wx = fx - (float)x0; int x1i = x0 + (x0 < WI - 1);
        const float* base = in + ((size_t)bc << 14);
        float v00 = base[y0 * WI + x0], v01 = base[y0 * WI + x1i];
        float v10 = base[y1i * WI + x0], v11 = base[y1i * WI + x1i];
        float r0 = v00 * (1.0f - wy) + v10 * wy;   // H first, then W (matches ref)
        float r1 = v01 * (1.0f - wy) + v11 * wy;
        out[idx] = r0 * (1.0f - wx) + r1 * wx;
    }
}

// ---------------- kernel 4: direct 3x3 conv, pad 1, 2-channel LDS chunks ----------------
// Tile: 64(W) x 32(H) outputs, 8 oc per block, 256 threads; tx=tid&15 -> 4 cols, ty=tid>>4 -> 2 rows.
// LDS 18.5-19.7 KB -> 8 blocks/CU by LDS; VGPR ~100 -> ~5 blocks/CU net (vs 2 at r2's 38.4 KB).
// UPS: fused align_corners bilinear x2 during staging (fallback when ws too small for `up`).
template<bool UPS, bool PER_BATCH, bool MISH, bool STATS>
__global__ __launch_bounds__(256) void conv3x3_kernel(
        const float* __restrict__ in, const float* __restrict__ wgt,
        float* __restrict__ out, float* __restrict__ stats,
        int OC, int ocShift) {
    __shared__ float smem[2][34][68];   // pitch 68: keeps float4 frags 16B-aligned
    __shared__ int   yot[34], ydt[34], xot[66], xdt[66];
    __shared__ float wyt[34], wxt[66];

    const int tid = threadIdx.x;
    const int tx = tid & 15, ty = tid >> 4;
    const int bid = blockIdx.x;
    const int tileX = bid & 3;
    const int tileY = (bid >> 2) & 7;
    const int rest = bid >> 5;
    const int ocT = rest & ((1 << ocShift) - 1);
    const int b = rest >> ocShift;
    const int row0 = tileY * 32, col0 = tileX * 64;

    if constexpr (UPS) {
        if (tid < 34) {
            int gy = row0 - 1 + tid;
            if ((unsigned)gy < 256u) {
                float fy = (float)gy * UP_STEP;
                int y0 = (int)fy;
                yot[tid] = y0 << 7;
                ydt[tid] = (y0 < HI - 1) ? WI : 0;
                wyt[tid] = fy - (float)y0;
            }
        } else if (tid >= 64 && tid < 130) {
            int xx = tid - 64;
            int gx = col0 - 1 + xx;
            if ((unsigned)gx < 256u) {
                float fx = (float)gx * UP_STEP;
                int x0 = (int)fx;
                xot[xx] = x0;
                xdt[xx] = (x0 < WI - 1) ? 1 : 0;
                wxt[xx] = fx - (float)x0;
            }
        }
        __syncthreads();
    }

    const float* wbase = wgt + ((PER_BATCH ? (size_t)b * OC : (size_t)0) + (size_t)(ocT << 3)) * (NC1 * 9);

    float acc[8][2][4];
    #pragma unroll
    for (int o = 0; o < 8; ++o)
        #pragma unroll
        for (int dy = 0; dy < 2; ++dy)
            #pragma unroll
            for (int dx = 0; dx < 4; ++dx) acc[o][dy][dx] = 0.f;

    for (int ch = 0; ch < NC1; ch += 2) {
        #pragma unroll
        for (int c = 0; c < 2; ++c) {
            if constexpr (UPS) {
                const float* ibase = in + ((size_t)(b * NC1 + ch + c) << 14);
                #pragma unroll 3
                for (int i = tid; i < 34 * 66; i += 256) {
                    int yy = i / 66;
                    int xx = i - yy * 66;
                    int gy = row0 - 1 + yy, gx = col0 - 1 + xx;
                    float v = 0.f;
                    if ((unsigned)gy < 256u && (unsigned)gx < 256u) {
                        int yo = yot[yy], yd = ydt[yy]; float wy = wyt[yy];
                        int xo = xot[xx], xd = xdt[xx]; float wx = wxt[xx];
                        const float* bp = ibase + yo + xo;
                        float v00 = bp[0], v01 = bp[xd];
                        float v10 = bp[yd], v11 = bp[yd + xd];
                        float r0 = v00 * (1.0f - wy) + v10 * wy;
                        float r1 = v01 * (1.0f - wy) + v11 * wy;
                        v = r0 * (1.0f - wx) + r1 * wx;
                    }
                    smem[c][yy][xx] = v;
                }
            } else {
                const float* ibase = in + ((size_t)(b * NC1 + ch + c) << 16);
                #pragma unroll 3
                for (int i = tid; i < 34 * 66; i += 256) {
                    int yy = i / 66;
                    int xx = i - yy * 66;
                    int gy = row0 - 1 + yy, gx = col0 - 1 + xx;
                    float v = 0.f;
                    if ((unsigned)gy < 256u && (unsigned)gx < 256u)
                        v = ibase[(gy << 8) + gx];
                    smem[c][yy][xx] = v;
                }
            }
        }
        __syncthreads();
        #pragma unroll
        for (int c = 0; c < 2; ++c) {
            float xi[4][6];
            #pragma unroll
            for (int r = 0; r < 4; ++r) {
                const float* rowp = &smem[c][2 * ty + r][4 * tx];
                float4 v4 = *reinterpret_cast<const float4*>(rowp);
                float2 v2 = *reinterpret_cast<const float2*>(rowp + 4);
                xi[r][0] = v4.x; xi[r][1] = v4.y; xi[r][2] = v4.z; xi[r][3] = v4.w;
                xi[r][4] = v2.x; xi[r][5] = v2.y;
            }
            #pragma unroll
            for (int o = 0; o < 8; ++o) {
                const float* wr = wbase + (size_t)(o * NC1 + ch + c) * 9;  // block-uniform -> s_load
                float w[9];
                #pragma unroll
                for (int k = 0; k < 9; ++k) w[k] = wr[k];
                #pragma unroll
                for (int kh = 0; kh < 3; ++kh)
                    #pragma unroll
                    for (int kw = 0; kw < 3; ++kw) {
                        float wv = w[kh * 3 + kw];
                        #pragma unroll
                        for (int dy = 0; dy < 2; ++dy)
                            #pragma unroll
                            for (int dx = 0; dx < 4; ++dx)
                                acc[o][dy][dx] = fmaf(xi[dy + kh][dx + kw], wv, acc[o][dy][dx]);
                    }
            }
        }
        __syncthreads();
    }

    #pragma unroll
    for (int o = 0; o < 8; ++o) {
        int ocg = (ocT << 3) + o;
        float* obase = out + (((size_t)(b * OC + ocg)) << 16) + ((size_t)(row0 + 2 * ty) << 8) + col0 + 4 * tx;
        #pragma unroll
        for (int dy = 0; dy < 2; ++dy) {
            float4 v;
            v.x = MISH ? mish_f(acc[o][dy][0]) : acc[o][dy][0];
            v.y = MISH ? mish_f(acc[o][dy][1]) : acc[o][dy][1];
            v.z = MISH ? mish_f(acc[o][dy][2]) : acc[o][dy][2];
            v.w = MISH ? mish_f(acc[o][dy][3]) : acc[o][dy][3];
            *reinterpret_cast<float4*>(obase + ((size_t)dy << 8)) = v;
        }
    }

    if constexpr (STATS) {
        #pragma unroll
        for (int o = 0; o < 8; ++o) {
            float s = 0.f, s2 = 0.f;
            #pragma unroll
            for (int dy = 0; dy < 2; ++dy)
                #pragma unroll
                for (int dx = 0; dx < 4; ++dx) { float v = acc[o][dy][dx]; s += v; s2 += v * v; }
            #pragma unroll
            for (int off = 1; off < 64; off <<= 1) {
                s += __shfl_xor(s, off);
                s2 += __shfl_xor(s2, off);
            }
            if ((tid & 63) == 0) {
                atomicAdd(&stats[2 * ((ocT << 3) + o) + 0], s);
                atomicAdd(&stats[2 * ((ocT << 3) + o) + 1], s2);
            }
        }
    }
}

// ---------------- kernel 5: BN finalize + residual add (in-place on d_out) ----------------
__global__ void final_kernel(float* __restrict__ out, const float* __restrict__ sc,
                             const float* __restrict__ stats, const float* __restrict__ gamma,
                             const float* __restrict__ beta) {
    const int n4 = B * NC2 * HO * WO / 4;
    const float inv_cnt = 1.0f / (float)(B * HO * WO);
    for (int i = blockIdx.x * blockDim.x + threadIdx.x; i < n4; i += gridDim.x * blockDim.x) {
        int c = (i >> 14) & 31;
        float mean = stats[2 * c] * inv_cnt;
        float var = stats[2 * c + 1] * inv_cnt - mean * mean;
        float g = gamma[c] * rsqrtf(var + EPS_BN_F);
        float bt = beta[c] - mean * g;     // sc conv bias cancels exactly in batch-stats BN
        float4 a = reinterpret_cast<float4*>(out)[i];
        float4 s = reinterpret_cast<const float4*>(sc)[i];
        float4 o;
        o.x = a.x + s.x * g + bt;
        o.y = a.y + s.y * g + bt;
        o.z = a.z + s.z * g + bt;
        o.w = a.w + s.w * g + bt;
        reinterpret_cast<float4*>(out)[i] = o;
    }
}

// ---------------- launch ----------------
extern "C" void kernel_launch(void* const* d_in, const int* in_sizes, int n_in,
                              void* d_out, int out_size, void* d_ws, size_t ws_size,
                              hipStream_t stream) {
    (void)in_sizes; (void)n_in; (void)out_size;
    const float* input   = (const float*)d_in[0];
    const float* z       = (const float*)d_in[1];
    const float* ws1_w   = (const float*)d_in[2];
    const float* ws1_b   = (const float*)d_in[3];
    const float* conv1_w = (const float*)d_in[4];
    const float* ws2_w   = (const float*)d_in[5];
    const float* ws2_b   = (const float*)d_in[6];
    const float* conv2_w = (const float*)d_in[7];
    const float* sc_w    = (const float*)d_in[8];
    // d_in[9] = sc_b: cancels exactly under training-mode BN (shifts mean only)
    const float* bn_gamma = (const float*)d_in[10];
    const float* bn_beta  = (const float*)d_in[11];

    float* ws   = (float*)d_ws;
    float* y1   = ws + OFF_Y1;
    float* y2   = ws + OFF_Y2;
    float* w1m  = ws + OFF_W1;
    float* w2m  = ws + OFF_W2;
    float* stats= ws + OFF_STATS;
    float* sc   = ws + OFF_SC;
    float* out1 = ws + OFF_OUT1;
    float* up   = ws + OFF_UP;
    float* outp = (float*)d_out;

    const bool mat = ws_size >= NEED_MAT_BYTES;   // constant across calls -> graph-safe

    hipMemsetAsync(stats, 0, 2 * NC2 * sizeof(float), stream);

    style_y_kernel<<<4, 256, 0, stream>>>(z, ws1_w, ws1_b, ws2_w, ws2_b, y1, y2);
    modulate_kernel<<<B * NC1 + B * NC2, 64, 0, stream>>>(conv1_w, conv2_w, y1, y2, w1m, w2m);

    if (mat) {
        upsample_kernel<<<2048, 256, 0, stream>>>(input, up);
        conv3x3_kernel<false, true, true, false><<<2048, 256, 0, stream>>>(up, w1m, out1, nullptr, NC1, 3);
        conv3x3_kernel<false, false, false, true><<<1024, 256, 0, stream>>>(up, sc_w, sc, stats, NC2, 2);
    } else {
        conv3x3_kernel<true, true, true, false><<<2048, 256, 0, stream>>>(input, w1m, out1, nullptr, NC1, 3);
        conv3x3_kernel<true, false, false, true><<<1024, 256, 0, stream>>>(input, sc_w, sc, stats, NC2, 2);
    }
    // conv2: out1 -> d_out, per-batch weights, mish
    conv3x3_kernel<false, true, true, false><<<1024, 256, 0, stream>>>(out1, w2m, outp, nullptr, NC2, 2);

    // out = conv2 + gamma_hat * sc + beta_hat   (in place on d_out)
    final_kernel<<<2048, 256, 0, stream>>>(outp, sc, stats, bn_gamma, bn_beta);
}

// Round 5
// 1960.166 us; speedup vs baseline: 1.9098x; 1.5191x over previous
//
#include <hip/hip_runtime.h>
#include <cstddef>

// ---------------- problem constants ----------------
constexpr int B = 8, NC1 = 64, NC2 = 32, ZD = 512;
constexpr float EPS_DEMOD_F = 1e-8f;
constexpr float EPS_BN_F = 1e-5f;
constexpr float UP_STEP = 127.0f / 255.0f;   // fp32 linspace step (matches passing r2/r3)

typedef __attribute__((ext_vector_type(8))) short s16x8;   // 8 bf16 (4 VGPRs)
typedef __attribute__((ext_vector_type(4))) float f32x4;
typedef unsigned int u32;
typedef unsigned short u16;

// ---------------- workspace layout (byte offsets) ----------------
constexpr size_t PLANE = 67108864;               // one NHWC bf16 plane: 8*256*256 px * 64ic * 2B
constexpr size_t OFF_Y1   = 0;                   // 512 f
constexpr size_t OFF_Y2   = 2048;
constexpr size_t OFF_STATS= 4096;                // 64 f
constexpr size_t OFF_W1H  = 8192;                // 294912 u16
constexpr size_t OFF_W1L  = OFF_W1H + 589824;
constexpr size_t OFF_W2H  = OFF_W1L + 589824;    // 147456 u16
constexpr size_t OFF_W2L  = OFF_W2H + 294912;
constexpr size_t OFF_WSH  = OFF_W2L + 294912;    // 18432 u16
constexpr size_t OFF_WSL  = OFF_WSH + 36864;
constexpr size_t OFF_PLANES = 2097152;           // 2MB aligned
constexpr size_t NEED_SPLIT = OFF_PLANES + 4 * PLANE;   // ~270.5 MB

// ---------------- helpers ----------------
__device__ __forceinline__ u16 f2bf(float x) {           // RNE fp32 -> bf16
    u32 u = __float_as_uint(x);
    return (u16)((u + 0x7FFFu + ((u >> 16) & 1u)) >> 16);
}
__device__ __forceinline__ float bf2f(u16 h) { return __uint_as_float(((u32)h) << 16); }

__device__ __forceinline__ float mish_f(float x) {
    if (x > 20.0f) return x;
    float e = expf(x);
    float a = 1.0f + e;
    float a2 = a * a;
    return x * (a2 - 1.0f) / (a2 + 1.0f);
}

// ---------------- kernel 1: y = z @ sw.T + sb ----------------
__global__ void style_y_kernel(const float* __restrict__ z,
                               const float* __restrict__ w1, const float* __restrict__ b1,
                               const float* __restrict__ w2, const float* __restrict__ b2,
                               float* __restrict__ y1, float* __restrict__ y2) {
    int gid = blockIdx.x * blockDim.x + threadIdx.x;
    if (gid >= 2 * B * NC1) return;
    int which = gid >> 9;
    int r = gid & 511;
    int b = r >> 6, c = r & 63;
    const float* w = which ? w2 : w1;
    const float* bias = which ? b2 : b1;
    const float* zr = z + (size_t)b * ZD;
    const float* wr = w + (size_t)c * ZD;
    float acc = 0.f;
    for (int k = 0; k < ZD; k += 4) {
        float4 zv = *reinterpret_cast<const float4*>(zr + k);
        float4 wv = *reinterpret_cast<const float4*>(wr + k);
        acc += zv.x * wv.x + zv.y * wv.y + zv.z * wv.z + zv.w * wv.w;
    }
    acc += bias[c];
    (which ? y2 : y1)[r] = acc;
}

// ---------------- kernel 2: modulate + demod + hi/lo split + MFMA-swizzle ----------------
// blocks: [0,512) conv1 (b,oc), [512,768) conv2 (b,oc), [768,800) shortcut (oc). 64 threads = ic.
// A-frag layout (16x16x32): lane = (oc&15) | (q<<4), q = (ic&31)>>3, elem e = ic&7, ck = ic>>5.
// plane layout: [b][tap][ck][ocgrp][lane][8]
__global__ void modulate_kernel(const float* __restrict__ conv1_w, const float* __restrict__ conv2_w,
                                const float* __restrict__ sc_w,
                                const float* __restrict__ y1, const float* __restrict__ y2,
                                u16* __restrict__ w1h, u16* __restrict__ w1l,
                                u16* __restrict__ w2h, u16* __restrict__ w2l,
                                u16* __restrict__ wsh, u16* __restrict__ wsl) {
    int bid = blockIdx.x;
    int ic = threadIdx.x;
    const float* src; u16 *dh, *dl; int oc, OCG; float m; bool demod;
    if (bid < 512) {
        int b = bid >> 6; oc = bid & 63; OCG = 4; demod = true;
        src = conv1_w + ((size_t)oc * 64 + ic) * 9;
        m = 1.0f + y1[b * 64 + ic];
        dh = w1h + (size_t)b * 36864; dl = w1l + (size_t)b * 36864;
    } else if (bid < 768) {
        int r = bid - 512; int b = r >> 5; oc = r & 31; OCG = 2; demod = true;
        src = conv2_w + ((size_t)oc * 64 + ic) * 9;
        m = 1.0f + y2[b * 64 + ic];
        dh = w2h + (size_t)b * 18432; dl = w2l + (size_t)b * 18432;
    } else {
        oc = bid - 768; OCG = 2; demod = false;
        src = sc_w + ((size_t)oc * 64 + ic) * 9;
        m = 1.0f; dh = wsh; dl = wsl;
    }
    float wv[9], ss = 0.f;
    #pragma unroll
    for (int k = 0; k < 9; ++k) { wv[k] = src[k] * m; ss += wv[k] * wv[k]; }
    #pragma unroll
    for (int off = 1; off < 64; off <<= 1) ss += __shfl_xor(ss, off);
    float d = demod ? rsqrtf(ss + EPS_DEMOD_F) : 1.0f;
    int lane = (oc & 15) | (((ic >> 3) & 3) << 4);
    int ck = ic >> 5, ocg = oc >> 4, e = ic & 7;
    #pragma unroll
    for (int tap = 0; tap < 9; ++tap) {
        float wq = wv[tap] * d;
        u16 h = f2bf(wq);
        u16 l = f2bf(wq - bf2f(h));
        size_t idx = ((((size_t)tap * 2 + ck) * OCG + ocg) * 64 + lane) * 8 + e;
        dh[idx] = h; dl[idx] = l;
    }
}

// ---------------- kernel 3: bilinear x2 upsample -> NHWC bf16 hi(/lo) planes ----------------
// block: 16x16 output px for one b; LDS stages 10x10 input window for all 64 ic.
template<bool SPLIT>
__global__ __launch_bounds__(256) void upsample_nhwc_kernel(const float* __restrict__ in,
                                                            u16* __restrict__ upH,
                                                            u16* __restrict__ upL) {
    __shared__ float L[64 * 101];   // [ic][10*10] pitch 101 (bank spread)
    int bid = blockIdx.x;
    int txt = bid & 15, tyt = (bid >> 4) & 15, b = bid >> 8;
    int row0 = tyt << 4, col0 = txt << 4;
    int iy0 = (int)(row0 * UP_STEP);
    int ix0 = (int)(col0 * UP_STEP);
    int tid = threadIdx.x;
    for (int i = tid; i < 6400; i += 256) {
        int ic = i / 100;
        int p = i - ic * 100;
        int iy = p / 10;
        int ix = p - iy * 10;
        int gy = min(iy0 + iy, 127), gx = min(ix0 + ix, 127);
        L[ic * 101 + p] = in[(((size_t)b * 64 + ic) << 14) + (gy << 7) + gx];
    }
    __syncthreads();
    int g = tid & 7, pbase = tid >> 3;
    for (int pp = 0; pp < 8; ++pp) {
        int pl = pbase + (pp << 5);
        int py = pl >> 4, px = pl & 15;
        int gy = row0 + py, gx = col0 + px;
        float fy = gy * UP_STEP; int y0 = (int)fy; float wy = fy - (float)y0;
        float fx = gx * UP_STEP; int x0 = (int)fx; float wx = fx - (float)x0;
        int ly = (y0 - iy0) * 10, lx = x0 - ix0;
        int ly1 = ly + ((y0 < 127) ? 10 : 0);
        int lx1 = lx + (x0 < 127);
        u32 hp[4], lp[4];
        #pragma unroll
        for (int e2 = 0; e2 < 4; ++e2) {
            u16 hh[2], ll[2];
            #pragma unroll
            for (int h = 0; h < 2; ++h) {
                int ic = g * 8 + e2 * 2 + h;
                const float* P = &L[ic * 101];
                float v00 = P[ly + lx], v01 = P[ly + lx1];
                float v10 = P[ly1 + lx], v11 = P[ly1 + lx1];
                float r0 = v00 * (1.0f - wy) + v10 * wy;   // H first, then W (matches ref)
                float r1 = v01 * (1.0f - wy) + v11 * wy;
                float v = r0 * (1.0f - wx) + r1 * wx;
                u16 hv = f2bf(v);
                hh[h] = hv;
                ll[h] = 0;
                if (SPLIT) ll[h] = f2bf(v - bf2f(hv));
            }
            hp[e2] = (u32)hh[0] | ((u32)hh[1] << 16);
            lp[e2] = (u32)ll[0] | ((u32)ll[1] << 16);
        }
        size_t rb = ((((size_t)b << 16) + ((size_t)gy << 8) + gx) << 6) + g * 8;
        *reinterpret_cast<uint4*>(upH + rb) = make_uint4(hp[0], hp[1], hp[2], hp[3]);
        if (SPLIT)
            *reinterpret_cast<uint4*>(upL + rb) = make_uint4(lp[0], lp[1], lp[2], lp[3]);
    }
}

// ---------------- kernel 4: MFMA 3x3 conv ----------------
// Strip: 4 rows x 64 cols output px per block (256 thr, 4 waves; wave w = row w). All OC per block.
// A = weights (M=oc, K=32ic), B = input px (N=16px).
// D layout (m89-verified): col=lane&15 -> px, row=(lane>>4)*4+reg -> oc.
// LDS: halo 6x66 px records; record = 32ic hi (+32ic lo), 16B-padded (RECB mult of 16).
template<int OCG, bool SPLIT, bool PER_B, bool DO_MISH, bool OUTSPLIT, bool STATS_>
__global__ __launch_bounds__(256) void conv_mfma_kernel(
        const u16* __restrict__ inH, const u16* __restrict__ inL,
        const u16* __restrict__ wH, const u16* __restrict__ wL,
        float* __restrict__ outF, u16* __restrict__ outH, u16* __restrict__ outL,
        float* __restrict__ stats) {
    constexpr int RECB = SPLIT ? 144 : 80;    // bytes per halo-px record
    __shared__ __align__(16) char lds[396 * RECB];
    const int tid = threadIdx.x;
    const int lane = tid & 63, w = tid >> 6;
    const int bid = blockIdx.x;
    const int ct = bid & 3, rt = (bid >> 2) & 63, b = bid >> 8;
    const int row0 = rt << 2, col0 = ct << 6;

    const u16* wHp = wH + (PER_B ? (size_t)b * (9 * 2 * OCG * 512) : 0);
    const u16* wLp = wL + (PER_B ? (size_t)b * (9 * 2 * OCG * 512) : 0);

    f32x4 acc[OCG][4];
    #pragma unroll
    for (int og = 0; og < OCG; ++og)
        #pragma unroll
        for (int pg = 0; pg < 4; ++pg) acc[og][pg] = f32x4{0.f, 0.f, 0.f, 0.f};

    for (int ck = 0; ck < 2; ++ck) {
        constexpr int NG = SPLIT ? 8 : 4;
        for (int j = tid; j < 396 * NG; j += 256) {
            int rec = j / NG;
            int g = j & (NG - 1);
            int hy = rec / 66;
            int hx = rec - hy * 66;
            int gy = row0 - 1 + hy, gx = col0 - 1 + hx;
            uint4 v = make_uint4(0, 0, 0, 0);
            if ((unsigned)gy < 256u && (unsigned)gx < 256u) {
                const u16* src = (SPLIT && g >= 4) ? inL : inH;
                size_t off = ((((size_t)b << 16) + ((size_t)gy << 8) + gx) << 6) + (ck << 5) + ((g & 3) << 3);
                v = *reinterpret_cast<const uint4*>(src + off);
            }
            *reinterpret_cast<uint4*>(lds + (size_t)rec * RECB + g * 16) = v;
        }
        __syncthreads();
        #pragma unroll
        for (int kh = 0; kh < 3; ++kh)
            #pragma unroll
            for (int kw = 0; kw < 3; ++kw) {
                const int tap = kh * 3 + kw;
                s16x8 wfh[OCG], wfl[OCG];
                size_t wbase = (((size_t)tap * 2 + ck) * OCG) * 512 + lane * 8;
                #pragma unroll
                for (int og = 0; og < OCG; ++og) {
                    wfh[og] = *reinterpret_cast<const s16x8*>(wHp + wbase + og * 512);
                    wfl[og] = *reinterpret_cast<const s16x8*>(wLp + wbase + og * 512);
                }
                const int recb = (w + kh) * 66 + kw + (lane & 15);
                const int qoff = (lane >> 4) << 4;
                #pragma unroll
                for (int pg = 0; pg < 4; ++pg) {
                    const char* rp = lds + (size_t)(recb + pg * 16) * RECB + qoff;
                    s16x8 ih = *reinterpret_cast<const s16x8*>(rp);
                    #pragma unroll
                    for (int og = 0; og < OCG; ++og) {
                        acc[og][pg] = __builtin_amdgcn_mfma_f32_16x16x32_bf16(wfh[og], ih, acc[og][pg], 0, 0, 0);
                        acc[og][pg] = __builtin_amdgcn_mfma_f32_16x16x32_bf16(wfl[og], ih, acc[og][pg], 0, 0, 0);
                    }
                    if (SPLIT) {
                        s16x8 il = *reinterpret_cast<const s16x8*>(rp + 64);
                        #pragma unroll
                        for (int og = 0; og < OCG; ++og)
                            acc[og][pg] = __builtin_amdgcn_mfma_f32_16x16x32_bf16(wfh[og], il, acc[og][pg], 0, 0, 0);
                    }
                }
            }
        __syncthreads();
    }

    // ---- epilogue ----
    const int q = lane >> 4;             // oc sub-group (D row block)
    const int cl = lane & 15;            // px within pg (D col)
    if (OUTSPLIT) {
        #pragma unroll
        for (int og = 0; og < OCG; ++og)
            #pragma unroll
            for (int pg = 0; pg < 4; ++pg) {
                int gx = col0 + pg * 16 + cl;
                size_t rb = ((((size_t)b << 16) + ((size_t)(row0 + w) << 8) + gx) << 6) + og * 16 + q * 4;
                u16 hh[4], ll[4];
                #pragma unroll
                for (int r = 0; r < 4; ++r) {
                    float v = acc[og][pg][r];
                    if (DO_MISH) v = mish_f(v);
                    u16 h = f2bf(v);
                    hh[r] = h;
                    ll[r] = 0;
                    if (SPLIT) ll[r] = f2bf(v - bf2f(h));
                }
                *reinterpret_cast<uint2*>(outH + rb) =
                    make_uint2((u32)hh[0] | ((u32)hh[1] << 16), (u32)hh[2] | ((u32)hh[3] << 16));
                if (SPLIT)
                    *reinterpret_cast<uint2*>(outL + rb) =
                        make_uint2((u32)ll[0] | ((u32)ll[1] << 16), (u32)ll[2] | ((u32)ll[3] << 16));
            }
    } else {
        #pragma unroll
        for (int og = 0; og < OCG; ++og)
            #pragma unroll
            for (int pg = 0; pg < 4; ++pg)
                #pragma unroll
                for (int r = 0; r < 4; ++r) {
                    float v = acc[og][pg][r];
                    if (DO_MISH) v = mish_f(v);
                    int oc = og * 16 + q * 4 + r;
                    outF[(((size_t)b * (OCG * 16) + oc) << 16) + ((size_t)(row0 + w) << 8) + col0 + pg * 16 + cl] = v;
                }
    }
    if (STATS_) {
        #pragma unroll
        for (int og = 0; og < OCG; ++og)
            #pragma unroll
            for (int r = 0; r < 4; ++r) {
                float s = 0.f, s2 = 0.f;
                #pragma unroll
                for (int pg = 0; pg < 4; ++pg) { float v = acc[og][pg][r]; s += v; s2 += v * v; }
                s += __shfl_xor(s, 1); s2 += __shfl_xor(s2, 1);
                s += __shfl_xor(s, 2); s2 += __shfl_xor(s2, 2);
                s += __shfl_xor(s, 4); s2 += __shfl_xor(s2, 4);
                s += __shfl_xor(s, 8); s2 += __shfl_xor(s2, 8);
                if (cl == 0) {
                    int oc = og * 16 + q * 4 + r;
                    atomicAdd(&stats[2 * oc], s);
                    atomicAdd(&stats[2 * oc + 1], s2);
                }
            }
    }
}

// ---------------- kernel 5: BN finalize + residual add (d_out holds sc) ----------------
__global__ void final_kernel(float* __restrict__ out, const float* __restrict__ c2,
                             const float* __restrict__ stats, const float* __restrict__ gamma,
                             const float* __restrict__ beta) {
    const int n4 = B * NC2 * 256 * 256 / 4;
    const float inv_cnt = 1.0f / (float)(B * 256 * 256);
    for (int i = blockIdx.x * blockDim.x + threadIdx.x; i < n4; i += gridDim.x * blockDim.x) {
        int c = (i >> 14) & 31;
        float mean = stats[2 * c] * inv_cnt;
        float var = stats[2 * c + 1] * inv_cnt - mean * mean;
        float g = gamma[c] * rsqrtf(var + EPS_BN_F);
        float bt = beta[c] - mean * g;     // sc conv bias cancels exactly in batch-stats BN
        float4 a = reinterpret_cast<const float4*>(c2)[i];
        float4 s = reinterpret_cast<float4*>(out)[i];
        float4 o;
        o.x = a.x + s.x * g + bt;
        o.y = a.y + s.y * g + bt;
        o.z = a.z + s.z * g + bt;
        o.w = a.w + s.w * g + bt;
        reinterpret_cast<float4*>(out)[i] = o;
    }
}

// ---------------- launch ----------------
extern "C" void kernel_launch(void* const* d_in, const int* in_sizes, int n_in,
                              void* d_out, int out_size, void* d_ws, size_t ws_size,
                              hipStream_t stream) {
    (void)in_sizes; (void)n_in; (void)out_size;
    const float* input   = (const float*)d_in[0];
    const float* z       = (const float*)d_in[1];
    const float* ws1_w   = (const float*)d_in[2];
    const float* ws1_b   = (const float*)d_in[3];
    const float* conv1_w = (const float*)d_in[4];
    const float* ws2_w   = (const float*)d_in[5];
    const float* ws2_b   = (const float*)d_in[6];
    const float* conv2_w = (const float*)d_in[7];
    const float* sc_w    = (const float*)d_in[8];
    // d_in[9] = sc_b: cancels exactly under training-mode BN
    const float* bn_gamma = (const float*)d_in[10];
    const float* bn_beta  = (const float*)d_in[11];

    char* ws = (char*)d_ws;
    float* y1    = (float*)(ws + OFF_Y1);
    float* y2    = (float*)(ws + OFF_Y2);
    float* stats = (float*)(ws + OFF_STATS);
    u16* w1h = (u16*)(ws + OFF_W1H);
    u16* w1l = (u16*)(ws + OFF_W1L);
    u16* w2h = (u16*)(ws + OFF_W2H);
    u16* w2l = (u16*)(ws + OFF_W2L);
    u16* wsh = (u16*)(ws + OFF_WSH);
    u16* wsl = (u16*)(ws + OFF_WSL);
    float* outp = (float*)d_out;

    const bool split = ws_size >= NEED_SPLIT;   // constant across calls -> graph-safe

    hipMemsetAsync(stats, 0, 2 * NC2 * sizeof(float), stream);
    style_y_kernel<<<4, 256, 0, stream>>>(z, ws1_w, ws1_b, ws2_w, ws2_b, y1, y2);
    modulate_kernel<<<800, 64, 0, stream>>>(conv1_w, conv2_w, sc_w, y1, y2, w1h, w1l, w2h, w2l, wsh, wsl);

    if (split) {
        u16* upH = (u16*)(ws + OFF_PLANES);
        u16* upL = (u16*)(ws + OFF_PLANES + PLANE);
        u16* o1H = (u16*)(ws + OFF_PLANES + 2 * PLANE);
        u16* o1L = (u16*)(ws + OFF_PLANES + 3 * PLANE);
        float* tmp2 = (float*)(ws + OFF_PLANES);        // conv2 out (64MB) aliases upH (dead after sc)
        upsample_nhwc_kernel<true><<<2048, 256, 0, stream>>>(input, upH, upL);
        // conv1: up -> out1 (NHWC hi/lo), mish, per-batch weights
        conv_mfma_kernel<4, true, true, true, true, false><<<2048, 256, 0, stream>>>(
            upH, upL, w1h, w1l, nullptr, o1H, o1L, nullptr);
        // shortcut: up -> d_out (fp32 NCHW), BN stats
        conv_mfma_kernel<2, true, false, false, false, true><<<2048, 256, 0, stream>>>(
            upH, upL, wsh, wsl, outp, nullptr, nullptr, stats);
        // conv2: out1 -> tmp2 (fp32 NCHW, aliases upH), mish
        conv_mfma_kernel<2, true, true, true, false, false><<<2048, 256, 0, stream>>>(
            o1H, o1L, w2h, w2l, tmp2, nullptr, nullptr, nullptr);
        final_kernel<<<2048, 256, 0, stream>>>(outp, tmp2, stats, bn_gamma, bn_beta);
    } else {
        // low-memory fallback: input hi only (weights still split) — ~130 MB ws
        u16* upH = (u16*)(ws + OFF_PLANES);
        u16* o1H = (u16*)(ws + OFF_PLANES + PLANE);
        float* tmp2 = (float*)(ws + OFF_PLANES);
        upsample_nhwc_kernel<false><<<2048, 256, 0, stream>>>(input, upH, nullptr);
        conv_mfma_kernel<4, false, true, true, true, false><<<2048, 256, 0, stream>>>(
            upH, nullptr, w1h, w1l, nullptr, o1H, nullptr, nullptr);
        conv_mfma_kernel<2, false, false, false, false, true><<<2048, 256, 0, stream>>>(
            upH, nullptr, wsh, wsl, outp, nullptr, nullptr, stats);
        conv_mfma_kernel<2, false, true, true, false, false><<<2048, 256, 0, stream>>>(
            o1H, nullptr, w2h, w2l, tmp2, nullptr, nullptr, nullptr);
        final_kernel<<<2048, 256, 0, stream>>>(outp, tmp2, stats, bn_gamma, bn_beta);
    }
}